// Round 2
// baseline (119.178 us; speedup 1.0000x reference)
//
#include <hip/hip_runtime.h>
#include <hip/hip_bf16.h>

#define NB   64
#define SL   1024
#define EMB  128
#define NSK  1000
#define TI   64
#define NS   2     // split of i-tiles per j-tile

// bf16 table layout in ws (elements):
#define AI_OFF 0
#define BI_OFF 256000
#define AS_OFF 512000
#define BS_OFF 640000
#define TB_ELEMS 768000
#define ACC_BYTE_OFF (TB_ELEMS * 2)   // acc: [NS][NB][SL] float = 512 KB

// byte offsets into the bf16 table blob
#define AI_B 0
#define BI_B 512000
#define AS_B 1024000
#define BS_B 1280000

using short8  = __attribute__((ext_vector_type(8))) short;
using floatx4 = __attribute__((ext_vector_type(4))) float;

// log5(x) = log2(x) * INV_LOG2_5
#define INV_LOG2_5 0.43067655807339306f

__device__ inline unsigned cvt2(float x, float y) {
    float2 f; f.x = x; f.y = y;
    __hip_bfloat162 h = __float22bfloat162_rn(f);
    unsigned u; __builtin_memcpy(&u, &h, sizeof(u));
    return u;
}

// ---- one-time fp32 -> bf16 table conversion (8 elems/thread) ----
extern "C" __global__ __launch_bounds__(256)
void cvt_tables(const float* __restrict__ ai, const float* __restrict__ bi,
                const float* __restrict__ as, const float* __restrict__ bs,
                unsigned short* __restrict__ dst)
{
    const int t = blockIdx.x * 256 + threadIdx.x;   // 96000 threads
    const long e = (long)t * 8;
    const float* src;
    if      (e < 256000) src = ai + e;
    else if (e < 512000) src = bi + (e - 256000);
    else if (e < 640000) src = as + (e - 512000);
    else                 src = bs + (e - 640000);
    float4 f0 = *(const float4*)src;
    float4 f1 = *(const float4*)(src + 4);
    uint4 pk;
    pk.x = cvt2(f0.x, f0.y); pk.y = cvt2(f0.z, f0.w);
    pk.z = cvt2(f1.x, f1.y); pk.w = cvt2(f1.z, f1.w);
    *(uint4*)(dst + e) = pk;
}

// exact fp32 path for duplicate-timestamp pairs (dt==0, i<j):
// contribution = alpha_dot * exp(beta' * 14.306765580733931)   [= -log(1e-10)/log(5)]
__device__ float fixup_pair(const float* __restrict__ air,
                            const float* __restrict__ bir,
                            const float* __restrict__ asr,
                            const float* __restrict__ bsr) {
    float da = 0.f, db = 0.f;
#pragma unroll 8
    for (int k = 0; k < EMB; k += 4) {
        float4 a  = *(const float4*)(air + k);
        float4 s  = *(const float4*)(asr + k);
        float4 bq = *(const float4*)(bir + k);
        float4 tt = *(const float4*)(bsr + k);
        da += a.x * s.x + a.y * s.y + a.z * s.z + a.w * s.w;
        db += bq.x * tt.x + bq.y * tt.y + bq.z * tt.z + bq.w * tt.w;
    }
    float beta = fminf(fmaxf(db + 1.f, 0.f), 10.f);
    return da * __expf(beta * 14.30676558073393f);
}

// ============================================================================
// hawkes_main v3: register-resident B (all 64 j per wave), A streamed straight
// from L2 tables with MFMA-layout gathers. No barriers in the hot loop.
//   wave w owns i-rows [it*64 + w*16, +16) of every tile -> zero A duplication.
//   B skill rows staged once block-wide through swizzled LDS (one barrier).
// ============================================================================
extern "C" __global__ __launch_bounds__(256, 2)
void hawkes_main(const int*   __restrict__ inp,     // (B,4,L) int32
                 const unsigned short* __restrict__ tb,  // bf16 tables
                 float*       __restrict__ acc)     // [NS][NB][SL] partials
{
    __shared__ uint4 ldsq[2048];                    // 32 KB: [mat 2][row 64][256B] swizzled
    char* ldsc = (char*)ldsq;

    const int bid  = blockIdx.x;
    const int b    = bid & (NB - 1);
    const int r    = bid >> 6;                 // 0..31
    const int jt   = 15 - (r >> 1);            // heavy tiles dispatch first
    const int s    = r & 1;
    const int tid  = threadIdx.x;
    const int w    = tid >> 6;                 // wave id
    const int l    = tid & 63;
    const int quad = l >> 4;
    const int col  = l & 15;
    const int wrow = w * 16;                   // wave's row offset inside a tile

    const int* __restrict__ binp = inp + b * 4 * SL;
    const char* __restrict__ tbc = (const char*)tb;

    const int jbase = jt * TI;

    // ---- per-lane j times (4 strips of 16 j) ----
    int tjv[4];
#pragma unroll
    for (int strip = 0; strip < 4; ++strip)
        tjv[strip] = binp[3 * SL + jbase + strip * 16 + col];

    // ---- stage skill rows of the block's 64 j into LDS (once) ----
    // thread (row = tid>>2, sq = tid&3) stages 64B of both mats, chunk-swizzled:
    // 16B chunk c of row r lives at slot c ^ (r&15).
    {
        const int row  = tid >> 2;
        const int sq   = tid & 3;
        const int skj  = binp[jbase + row];
        const char* srcA = tbc + AS_B + (long)skj * 256 + sq * 64;
        const char* srcB = tbc + BS_B + (long)skj * 256 + sq * 64;
        uint4 qa[4], qb[4];
#pragma unroll
        for (int u = 0; u < 4; ++u) {
            qa[u] = *(const uint4*)(srcA + u * 16);
            qb[u] = *(const uint4*)(srcB + u * 16);
        }
        const int rx = (row & 15) << 4;
        const int wb = row * 256;
#pragma unroll
        for (int u = 0; u < 4; ++u) {
            const int slot = (((4 * sq + u) << 4) ^ rx);
            *(uint4*)(ldsc + wb + slot)         = qa[u];
            *(uint4*)(ldsc + 16384 + wb + slot) = qb[u];
        }
    }
    __syncthreads();

    // ---- gather B fragments for all 4 strips into registers (128 VGPRs) ----
    // B lane layout (16x16x32): lane(quad,col) holds row=col(+strip*16), k=quad*8+ks*32
    short8 bfa[4][4], bfb[4][4];
#pragma unroll
    for (int strip = 0; strip < 4; ++strip) {
        const int row   = strip * 16 + col;
        const int rbase = row * 256;
        const int rx    = (row & 15) << 4;
#pragma unroll
        for (int ks = 0; ks < 4; ++ks) {
            const int cb = ((quad + ks * 4) << 4) ^ rx;
            bfa[strip][ks] = *(const short8*)(ldsc + rbase + cb);
            bfb[strip][ks] = *(const short8*)(ldsc + 16384 + rbase + cb);
        }
    }

    // ---- pre-gather interaction indices for all (<=8) tiles: kills the
    //      binp -> table pointer-chase inside the loop ----
    int intrv[8];
#pragma unroll
    for (int tt = 0; tt < 8; ++tt) {
        const int arow = (s + 2 * tt) * TI + wrow + col;   // always < 1024
        intrv[tt] = binp[arow] + binp[2 * SL + arow] * NSK;
    }

    float sum[4] = {0.f, 0.f, 0.f, 0.f};

#pragma unroll 1
    for (int it = s; it <= jt; it += NS) {
        const int tt = (it - s) >> 1;
        // A-fragment gather straight from L2: lane(quad,col) reads row=col's
        // interaction row, bytes quad*16 + ks*64 (matches MFMA A layout).
        const long ab = (long)intrv[tt] * 256 + quad * 16;
        const char* pA = tbc + AI_B + ab;
        const char* pB = tbc + BI_B + ab;
        short8 av[4], bv[4];
#pragma unroll
        for (int ks = 0; ks < 4; ++ks) {
            av[ks] = *(const short8*)(pA + ks * 64);
            bv[ks] = *(const short8*)(pB + ks * 64);
        }
        const int4 t4 = *(const int4*)(binp + 3 * SL + it * TI + wrow + quad * 4);

        floatx4 aa[4], bb[4];
#pragma unroll
        for (int strip = 0; strip < 4; ++strip) {
            aa[strip] = floatx4{0.f, 0.f, 0.f, 0.f};
            bb[strip] = floatx4{1.f, 1.f, 1.f, 1.f};   // folds the "+1.0"
        }
#pragma unroll
        for (int ks = 0; ks < 4; ++ks) {
#pragma unroll
            for (int strip = 0; strip < 4; ++strip) {
                aa[strip] = __builtin_amdgcn_mfma_f32_16x16x32_bf16(av[ks], bfa[strip][ks], aa[strip], 0, 0, 0);
                bb[strip] = __builtin_amdgcn_mfma_f32_16x16x32_bf16(bv[ks], bfb[strip][ks], bb[strip], 0, 0, 0);
            }
        }

        // epilogue: C row = i (quad*4+rr within wave's 16 rows), col = j
#pragma unroll
        for (int strip = 0; strip < 4; ++strip) {
            const int tjs = tjv[strip];
#pragma unroll
            for (int rr = 0; rr < 4; ++rr) {
                const int ti = (rr == 0) ? t4.x : (rr == 1) ? t4.y : (rr == 2) ? t4.z : t4.w;
                const int dt = tjs - ti;
                // sorted times => (i<j && dt>0) <=> dt>0 ; dt==0 (dup) in finalize
                float lc  = __log2f((float)dt);                   // junk if dt<=0, discarded
                float nb  = fminf(fmaxf(bb[strip][rr], 0.f), 10.f) * (-INV_LOG2_5);
                float arg = (dt > 0) ? nb * lc : -__builtin_inff();
                sum[strip] += aa[strip][rr] * __builtin_amdgcn_exp2f(arg);
            }
        }
    }

    // ---- reduce: butterfly over quads, then cross-wave via (reused) LDS ----
#pragma unroll
    for (int strip = 0; strip < 4; ++strip) {
        sum[strip] += __shfl_xor(sum[strip], 16, 64);
        sum[strip] += __shfl_xor(sum[strip], 32, 64);
    }
    __syncthreads();                                   // B-LDS dead; reuse as red[4][64]
    float* red = (float*)ldsc;
    red[w * 64 + quad * 16 + col] = sum[quad];
    __syncthreads();
    if (w == 0) {
        const float tot = red[l] + red[64 + l] + red[128 + l] + red[192 + l];
        acc[(((long)s * NB + b) << 10) + jbase + l] = tot;
    }
}

extern "C" __global__ __launch_bounds__(256)
void hawkes_finalize(const int* __restrict__ inp, const float* __restrict__ pbase,
                     const float* __restrict__ sbase,
                     const float* __restrict__ ai, const float* __restrict__ as,
                     const float* __restrict__ bi, const float* __restrict__ bs,
                     const float* __restrict__ acc, float* __restrict__ out)
{
    const int t = blockIdx.x * 256 + threadIdx.x;   // 65536
    const int b = t >> 10, j = t & (SL - 1);
    const int* binp = inp + b * 4 * SL;
    const int tj   = binp[3 * SL + j];
    const int sk_j = binp[j];

    // exact fp32 correction for duplicate-timestamp pairs (adjacent in sorted order)
    float corr = 0.f;
    for (int i = j - 1; i >= 0 && binp[3 * SL + i] == tj; --i) {
        const int ski = binp[i], li = binp[2 * SL + i];
        const long intr = ski + (long)li * NSK;
        corr += fixup_pair(ai + intr * EMB, bi + intr * EMB,
                           as + (long)sk_j * EMB, bs + (long)sk_j * EMB);
    }

    float sum = acc[t] + acc[NB * SL + t] + corr;
    const float x = pbase[binp[SL + j]] + sbase[sk_j] + sum;
    out[t] = 1.f / (1.f + __expf(-x));
}

extern "C" void kernel_launch(void* const* d_in, const int* in_sizes, int n_in,
                              void* d_out, int out_size, void* d_ws, size_t ws_size,
                              hipStream_t stream) {
    const int*   inp = (const int*)d_in[0];
    const float* pb  = (const float*)d_in[1];
    const float* sb  = (const float*)d_in[2];
    const float* ai  = (const float*)d_in[3];
    const float* as  = (const float*)d_in[4];
    const float* bi  = (const float*)d_in[5];
    const float* bs  = (const float*)d_in[6];

    unsigned short* tb  = (unsigned short*)d_ws;
    float*          acc = (float*)((char*)d_ws + ACC_BYTE_OFF);

    cvt_tables<<<dim3(96000 / 256), dim3(256), 0, stream>>>(ai, bi, as, bs, tb);
    hawkes_main<<<dim3(NB * 16 * NS), dim3(256), 0, stream>>>(inp, tb, acc);
    hawkes_finalize<<<dim3(NB * SL / 256), dim3(256), 0, stream>>>(
        inp, pb, sb, ai, as, bi, bs, acc, (float*)d_out);
}

// Round 3
// 116.379 us; speedup vs baseline: 1.0241x; 1.0241x over previous
//
#include <hip/hip_runtime.h>
#include <hip/hip_bf16.h>

#define NB   64
#define SL   1024
#define EMB  128
#define NSK  1000
#define TI   64
#define NS   2     // split of i-tiles per j-tile

#define TB_ELEMS 768000
#define ACC_BYTE_OFF (TB_ELEMS * 2)   // acc: [NS][NB][SL] float = 512 KB

// byte offsets into the bf16 table blob
#define AI_B 0
#define BI_B 512000
#define AS_B 1024000
#define BS_B 1280000

using short8  = __attribute__((ext_vector_type(8))) short;
using floatx4 = __attribute__((ext_vector_type(4))) float;

// log5(x) = log2(x) * INV_LOG2_5
#define INV_LOG2_5 0.43067655807339306f

__device__ inline unsigned cvt2(float x, float y) {
    float2 f; f.x = x; f.y = y;
    __hip_bfloat162 h = __float22bfloat162_rn(f);
    unsigned u; __builtin_memcpy(&u, &h, sizeof(u));
    return u;
}

// ---- one-time fp32 -> bf16 table conversion (8 elems/thread) ----
extern "C" __global__ __launch_bounds__(256)
void cvt_tables(const float* __restrict__ ai, const float* __restrict__ bi,
                const float* __restrict__ as, const float* __restrict__ bs,
                unsigned short* __restrict__ dst)
{
    const int t = blockIdx.x * 256 + threadIdx.x;   // 96000 threads
    const long e = (long)t * 8;
    const float* src;
    if      (e < 256000) src = ai + e;
    else if (e < 512000) src = bi + (e - 256000);
    else if (e < 640000) src = as + (e - 512000);
    else                 src = bs + (e - 640000);
    float4 f0 = *(const float4*)src;
    float4 f1 = *(const float4*)(src + 4);
    uint4 pk;
    pk.x = cvt2(f0.x, f0.y); pk.y = cvt2(f0.z, f0.w);
    pk.z = cvt2(f1.x, f1.y); pk.w = cvt2(f1.z, f1.w);
    *(uint4*)(dst + e) = pk;
}

// exact fp32 path for duplicate-timestamp pairs (dt==0, i<j)
__device__ float fixup_pair(const float* __restrict__ air,
                            const float* __restrict__ bir,
                            const float* __restrict__ asr,
                            const float* __restrict__ bsr) {
    float da = 0.f, db = 0.f;
#pragma unroll 8
    for (int k = 0; k < EMB; k += 4) {
        float4 a  = *(const float4*)(air + k);
        float4 s  = *(const float4*)(asr + k);
        float4 bq = *(const float4*)(bir + k);
        float4 tt = *(const float4*)(bsr + k);
        da += a.x * s.x + a.y * s.y + a.z * s.z + a.w * s.w;
        db += bq.x * tt.x + bq.y * tt.y + bq.z * tt.z + bq.w * tt.w;
    }
    float beta = fminf(fmaxf(db + 1.f, 0.f), 10.f);
    return da * __expf(beta * 14.30676558073393f);
}

// ---- per-tile staging: thread carries 64B of BOTH mats for one row ----
struct Stage2 { uint4 a0, a1, a2, a3, b0, b1, b2, b3; };

__device__ __forceinline__ Stage2 stage_load2(const char* __restrict__ tbc,
                                              int intr, int sq)
{
    const long ab = (long)intr * 256 + sq * 64;
    const char* pA = tbc + AI_B + ab;
    const char* pB = tbc + BI_B + ab;
    Stage2 s;
    s.a0 = *(const uint4*)(pA);      s.a1 = *(const uint4*)(pA + 16);
    s.a2 = *(const uint4*)(pA + 32); s.a3 = *(const uint4*)(pA + 48);
    s.b0 = *(const uint4*)(pB);      s.b1 = *(const uint4*)(pB + 16);
    s.b2 = *(const uint4*)(pB + 32); s.b3 = *(const uint4*)(pB + 48);
    return s;
}

// Round-1 proven swizzle (measured 0 conflicts): chunk c of row r at byte
// (((c>>1)^(r&7)) + ((c&1)<<3))<<4 within the row's 256B.
__device__ __forceinline__ void stage_write2(char* buf, int srow, int wslot,
                                             const Stage2& s)
{
    char* pA = buf + srow * 256 + wslot;             // mat A  (chunks 4sq,4sq+1)
    char* pAx = buf + srow * 256 + (wslot ^ 16);     //        (chunks 4sq+2,4sq+3)
    *(uint4*)(pA)        = s.a0;  *(uint4*)(pA + 128)  = s.a1;
    *(uint4*)(pAx)       = s.a2;  *(uint4*)(pAx + 128) = s.a3;
    *(uint4*)(pA + 16384)  = s.b0;  *(uint4*)(pA + 16384 + 128)  = s.b1;
    *(uint4*)(pAx + 16384) = s.b2;  *(uint4*)(pAx + 16384 + 128) = s.b3;
}

// ============================================================================
// hawkes_main v5: B for all 64 j in registers (round-2, proven) + A through
// double-buffered swizzled LDS with full-tile register prefetch (round-1,
// proven). Wave w owns i-rows [w*16, w*16+16) of each 64-row tile -> each
// tile's LDS bytes are read exactly once. One barrier per tile.
// ============================================================================
extern "C" __global__ __launch_bounds__(256, 2)
void hawkes_main(const int*   __restrict__ inp,     // (B,4,L) int32
                 const unsigned short* __restrict__ tb,  // bf16 tables
                 float*       __restrict__ acc)     // [NS][NB][SL] partials
{
    __shared__ uint4 ldsq[4096];                    // 64 KB: 2 bufs x 2 mats x 64 rows x 256B
    char* ldsc = (char*)ldsq;

    const int bid  = blockIdx.x;
    const int b    = bid & (NB - 1);
    const int r    = bid >> 6;                 // 0..31
    const int jt   = 15 - (r >> 1);            // heavy tiles dispatch first
    const int s    = r & 1;
    const int tid  = threadIdx.x;
    const int w    = tid >> 6;                 // wave id
    const int l    = tid & 63;
    const int quad = l >> 4;
    const int col  = l & 15;
    const int wrow = w * 16;                   // wave's i-slab inside a tile

    const int* __restrict__ binp = inp + b * 4 * SL;
    const char* __restrict__ tbc = (const char*)tb;
    const int jbase = jt * TI;

    // ---- per-lane j times (4 strips of 16 j) ----
    int tjv[4];
#pragma unroll
    for (int strip = 0; strip < 4; ++strip)
        tjv[strip] = binp[3 * SL + jbase + strip * 16 + col];

    // ---- stage skill rows of the block's 64 j into LDS (once; round-2 code) ----
    {
        const int row  = tid >> 2;
        const int sq   = tid & 3;
        const int skj  = binp[jbase + row];
        const char* srcA = tbc + AS_B + (long)skj * 256 + sq * 64;
        const char* srcB = tbc + BS_B + (long)skj * 256 + sq * 64;
        uint4 qa[4], qb[4];
#pragma unroll
        for (int u = 0; u < 4; ++u) {
            qa[u] = *(const uint4*)(srcA + u * 16);
            qb[u] = *(const uint4*)(srcB + u * 16);
        }
        const int rx = (row & 15) << 4;
        const int wb = row * 256;
#pragma unroll
        for (int u = 0; u < 4; ++u) {
            const int slot = (((4 * sq + u) << 4) ^ rx);
            *(uint4*)(ldsc + wb + slot)         = qa[u];
            *(uint4*)(ldsc + 16384 + wb + slot) = qb[u];
        }
    }
    __syncthreads();

    // ---- B fragments for all 4 strips -> registers (round-2, proven) ----
    short8 bfa[4][4], bfb[4][4];
#pragma unroll
    for (int strip = 0; strip < 4; ++strip) {
        const int row   = strip * 16 + col;
        const int rbase = row * 256;
        const int rx    = (row & 15) << 4;
#pragma unroll
        for (int ks = 0; ks < 4; ++ks) {
            const int cb = ((quad + ks * 4) << 4) ^ rx;
            bfa[strip][ks] = *(const short8*)(ldsc + rbase + cb);
            bfb[strip][ks] = *(const short8*)(ldsc + 16384 + rbase + cb);
        }
    }

    // ---- staging role + pre-gathered interaction indices (<=8 tiles) ----
    const int srow  = tid >> 2;                // row within tile
    const int sq    = tid & 3;
    const int wslot = (((2 * sq) ^ (srow & 7)) << 4);
    int intrv[8];
#pragma unroll
    for (int tt = 0; tt < 8; ++tt) {
        const int arow = (s + 2 * tt) * TI + srow;   // always < 1024
        intrv[tt] = binp[arow] + binp[2 * SL + arow] * NSK;
    }

    // ---- lane-invariant swizzled read offsets for the wave's i-slab ----
    int roff[4];
    {
        const int qh = quad >> 1, ql = quad & 1, c7 = col & 7;
#pragma unroll
        for (int ks = 0; ks < 4; ++ks)
            roff[ks] = (wrow + col) * 256 + ql * 128 + (((2 * ks + qh) ^ c7) << 4);
    }

    float sum[4] = {0.f, 0.f, 0.f, 0.f};

    if (s <= jt) {
        const int nt = ((jt - s) >> 1) + 1;

        Stage2 rS = stage_load2(tbc, intrv[0], sq);
        __syncthreads();                         // B-frag reads done block-wide
        stage_write2(ldsc, srow, wslot, rS);     // buf0 <- tile 0
        if (nt > 1) rS = stage_load2(tbc, intrv[1], sq);

#pragma unroll 1
        for (int t = 0; t < nt; ++t) {
            __syncthreads();                     // publishes buf(t&1); prev compute done
            const int cur = (t & 1) << 15;
            if (t + 1 < nt) stage_write2(ldsc + (cur ^ 32768), srow, wslot, rS);
            if (t + 2 < nt) rS = stage_load2(tbc, intrv[t + 2], sq);

            const int it = s + 2 * t;
            const char* bufA = ldsc + cur;
            short8 av[4], bv[4];
#pragma unroll
            for (int ks = 0; ks < 4; ++ks) {
                av[ks] = *(const short8*)(bufA + roff[ks]);
                bv[ks] = *(const short8*)(bufA + 16384 + roff[ks]);
            }
            const int4 t4 = *(const int4*)(binp + 3 * SL + it * TI + wrow + quad * 4);

            floatx4 aa[4], bb[4];
#pragma unroll
            for (int strip = 0; strip < 4; ++strip) {
                aa[strip] = floatx4{0.f, 0.f, 0.f, 0.f};
                bb[strip] = floatx4{1.f, 1.f, 1.f, 1.f};   // folds the "+1.0"
            }
#pragma unroll
            for (int ks = 0; ks < 4; ++ks) {
#pragma unroll
                for (int strip = 0; strip < 4; ++strip) {
                    aa[strip] = __builtin_amdgcn_mfma_f32_16x16x32_bf16(av[ks], bfa[strip][ks], aa[strip], 0, 0, 0);
                    bb[strip] = __builtin_amdgcn_mfma_f32_16x16x32_bf16(bv[ks], bfb[strip][ks], bb[strip], 0, 0, 0);
                }
            }

            // epilogue: C row = i (quad*4+rr in wave's slab), col = j
#pragma unroll
            for (int strip = 0; strip < 4; ++strip) {
                const int tjs = tjv[strip];
#pragma unroll
                for (int rr = 0; rr < 4; ++rr) {
                    const int ti = (rr == 0) ? t4.x : (rr == 1) ? t4.y : (rr == 2) ? t4.z : t4.w;
                    const int dt = tjs - ti;
                    // sorted => (i<j && dt>0) <=> dt>0 ; dt==0 handled in finalize
                    float lc  = __log2f((float)dt);               // junk if dt<=0, discarded
                    float nb  = fminf(fmaxf(bb[strip][rr], 0.f), 10.f) * (-INV_LOG2_5);
                    float arg = (dt > 0) ? nb * lc : -__builtin_inff();
                    sum[strip] += aa[strip][rr] * __builtin_amdgcn_exp2f(arg);
                }
            }
        }
    }

    // ---- reduce: butterfly over quads, then cross-wave via (reused) LDS ----
#pragma unroll
    for (int strip = 0; strip < 4; ++strip) {
        sum[strip] += __shfl_xor(sum[strip], 16, 64);
        sum[strip] += __shfl_xor(sum[strip], 32, 64);
    }
    __syncthreads();                                   // tile LDS dead; reuse as red[4][64]
    float* red = (float*)ldsc;
    red[w * 64 + quad * 16 + col] = sum[quad];
    __syncthreads();
    if (w == 0) {
        const float tot = red[l] + red[64 + l] + red[128 + l] + red[192 + l];
        acc[(((long)s * NB + b) << 10) + jbase + l] = tot;
    }
}

extern "C" __global__ __launch_bounds__(256)
void hawkes_finalize(const int* __restrict__ inp, const float* __restrict__ pbase,
                     const float* __restrict__ sbase,
                     const float* __restrict__ ai, const float* __restrict__ as,
                     const float* __restrict__ bi, const float* __restrict__ bs,
                     const float* __restrict__ acc, float* __restrict__ out)
{
    const int t = blockIdx.x * 256 + threadIdx.x;   // 65536
    const int b = t >> 10, j = t & (SL - 1);
    const int* binp = inp + b * 4 * SL;
    const int tj   = binp[3 * SL + j];
    const int sk_j = binp[j];

    // exact fp32 correction for duplicate-timestamp pairs (adjacent in sorted order)
    float corr = 0.f;
    for (int i = j - 1; i >= 0 && binp[3 * SL + i] == tj; --i) {
        const int ski = binp[i], li = binp[2 * SL + i];
        const long intr = ski + (long)li * NSK;
        corr += fixup_pair(ai + intr * EMB, bi + intr * EMB,
                           as + (long)sk_j * EMB, bs + (long)sk_j * EMB);
    }

    float sum = acc[t] + acc[NB * SL + t] + corr;
    const float x = pbase[binp[SL + j]] + sbase[sk_j] + sum;
    out[t] = 1.f / (1.f + __expf(-x));
}

extern "C" void kernel_launch(void* const* d_in, const int* in_sizes, int n_in,
                              void* d_out, int out_size, void* d_ws, size_t ws_size,
                              hipStream_t stream) {
    const int*   inp = (const int*)d_in[0];
    const float* pb  = (const float*)d_in[1];
    const float* sb  = (const float*)d_in[2];
    const float* ai  = (const float*)d_in[3];
    const float* as  = (const float*)d_in[4];
    const float* bi  = (const float*)d_in[5];
    const float* bs  = (const float*)d_in[6];

    unsigned short* tb  = (unsigned short*)d_ws;
    float*          acc = (float*)((char*)d_ws + ACC_BYTE_OFF);

    cvt_tables<<<dim3(96000 / 256), dim3(256), 0, stream>>>(ai, bi, as, bs, tb);
    hawkes_main<<<dim3(NB * 16 * NS), dim3(256), 0, stream>>>(inp, tb, acc);
    hawkes_finalize<<<dim3(NB * SL / 256), dim3(256), 0, stream>>>(
        inp, pb, sb, ai, as, bi, bs, acc, (float*)d_out);
}